// Round 10
// baseline (250.034 us; speedup 1.0000x reference)
//
#include <hip/hip_runtime.h>
#include <hip/hip_fp16.h>

#define N_NODES 50000
#define N_EDGES 800000
#define IN_F 64
#define H_F 128
#define NBUK 98          // node buckets of 512: bucket = dst >> 9
#define CAPB 12288       // fixed per-bucket record capacity (mean 8163, +45 sigma)
#define EPB 2048         // edges per block in part_k
#define NBLK 391         // ceil(N_EDGES / EPB)

typedef unsigned short u16;
typedef unsigned int u32;

static __device__ __forceinline__ float4 ld4(const float* p) {
    return *reinterpret_cast<const float4*>(p);
}
static __device__ __forceinline__ void st4(float* p, float4 v) {
    *reinterpret_cast<float4*>(p) = v;
}
// pack float4 -> 4 fp16 (8 B store)
static __device__ __forceinline__ void st_h4(__half* p, float4 v) {
    union { __half h[4]; uint2 u; } pk;
    pk.h[0] = __float2half_rn(v.x);
    pk.h[1] = __float2half_rn(v.y);
    pk.h[2] = __float2half_rn(v.z);
    pk.h[3] = __float2half_rn(v.w);
    *reinterpret_cast<uint2*>(p) = pk.u;
}
// acc(8 floats in two float4) += 8 halfs packed in uint4
static __device__ __forceinline__ void add_h8(float4& a, float4& b, uint4 r) {
    __half2* p = reinterpret_cast<__half2*>(&r);
    float2 f0 = __half22float2(p[0]);
    float2 f1 = __half22float2(p[1]);
    float2 f2 = __half22float2(p[2]);
    float2 f3 = __half22float2(p[3]);
    a.x += f0.x; a.y += f0.y; a.z += f1.x; a.w += f1.y;
    b.x += f2.x; b.y += f2.y; b.z += f3.x; b.w += f3.y;
}

// ---------- part_k: single-pass bucket partition (both graphs) + fused y = f*m*ng
__global__ __launch_bounds__(256) void part_k(
    const int* __restrict__ src_g, const int* __restrict__ dst_g, u32* __restrict__ rec_g,
    const int* __restrict__ src_f, const int* __restrict__ dst_f, u32* __restrict__ rec_f,
    int* __restrict__ bukcur,
    const float* __restrict__ f, const float* __restrict__ m,
    const float* __restrict__ ng, __half* __restrict__ y)
{
    __shared__ int c[NBUK];
    __shared__ int base[NBUK];
    const int tid = threadIdx.x;
    const int graph = blockIdx.x >= NBLK;
    const int blk = blockIdx.x - graph * NBLK;
    const int* src = graph ? src_f : src_g;
    const int* dst = graph ? dst_f : dst_g;
    u32* rec = graph ? rec_f : rec_g;
    int* cur = bukcur + graph * NBUK;

    if (tid < NBUK) c[tid] = 0;
    __syncthreads();
    const int e0 = blk * EPB;
    const int e1 = min(e0 + EPB, N_EDGES);

    u32 r_[8];
    bool v_[8];
#pragma unroll
    for (int j = 0; j < 8; ++j) {
        int e = e0 + tid + j * 256;
        v_[j] = (e < e1);
        int d = 0, s = 0;
        if (v_[j]) { d = dst[e]; s = src[e]; }
        r_[j] = ((u32)s << 16) | (u32)d;
        if (v_[j]) atomicAdd(&c[d >> 9], 1);
    }
    __syncthreads();
    if (tid < NBUK) base[tid] = atomicAdd(&cur[tid], c[tid]);
    __syncthreads();
    if (tid < NBUK) c[tid] = 0;                   // reuse as local cursor
    __syncthreads();
#pragma unroll
    for (int j = 0; j < 8; ++j) {
        if (v_[j]) {
            u32 r = r_[j];
            int b = (int)((r & 0xFFFFu) >> 9);
            int p = base[b] + atomicAdd(&c[b], 1);
            if (p < CAPB) rec[b * CAPB + p] = r;  // guard: drop on (impossible) overflow
        }
    }
    // fused: y = features * mask * ng, stored fp16
    for (int i = blockIdx.x * 256 + tid; i < N_NODES * (IN_F / 4);
         i += gridDim.x * 256) {
        int n = i >> 4;
        float s = ng[n];
        float4 a = ld4(f + 4 * i);
        float4 b = ld4(m + 4 * i);
        float4 r;
        r.x = a.x * b.x * s; r.y = a.y * b.y * s;
        r.z = a.z * b.z * s; r.w = a.w * b.w * s;
        st_h4(y + 4 * i, r);
    }
}

// ---------- P3: per-bucket LDS hist + scan -> rps/rpe; LDS-cursor scatter -> adj
__global__ __launch_bounds__(512) void p3_build_k(
    const u32* __restrict__ rec_g, int* __restrict__ rps_g, int* __restrict__ rpe_g,
    u16* __restrict__ adj_g,
    const u32* __restrict__ rec_f, int* __restrict__ rps_f, int* __restrict__ rpe_f,
    u16* __restrict__ adj_f,
    const int* __restrict__ bukcur)
{
    __shared__ int hist[512];
    __shared__ int tmp[512];
    const int tid = threadIdx.x;
    const int graph = blockIdx.x >= NBUK;
    const int b = blockIdx.x - graph * NBUK;
    const u32* rec = graph ? rec_f : rec_g;
    int* rps = graph ? rps_f : rps_g;
    int* rpe = graph ? rpe_f : rpe_g;
    u16* adj = graph ? adj_f : adj_g;
    const int e_base = b * CAPB;
    const int e_cnt  = min(bukcur[graph * NBUK + b], CAPB);

    hist[tid] = 0;
    __syncthreads();
    for (int i = tid; i < e_cnt; i += 512)
        atomicAdd(&hist[rec[e_base + i] & 511], 1);
    __syncthreads();
    const int v = hist[tid];
    tmp[tid] = v;
    __syncthreads();
    for (int o = 1; o < 512; o <<= 1) {
        int t = (tid >= o) ? tmp[tid - o] : 0;
        __syncthreads();
        tmp[tid] += t;
        __syncthreads();
    }
    const int incl = tmp[tid];
    const int excl = incl - v;
    const int n = (b << 9) + tid;
    if (n < N_NODES) {
        rps[n] = e_base + excl;
        rpe[n] = e_base + incl;
    }
    hist[tid] = excl;                             // becomes cursor
    __syncthreads();
    for (int i = tid; i < e_cnt; i += 512) {
        u32 r = rec[e_base + i];
        int p = atomicAdd(&hist[r & 511], 1);
        adj[e_base + p] = (u16)(r >> 16);
    }
}

// ---------- fused MLP: hb0 = fp16( ng * (relu( aggG(y)@W1 * ng + b1 ) @ wh) ) ----
// Per 64-node block: CSR-gather y into Al (fp32 LDS), GEMM1 (K=64,N=128),
// relu+scale -> Ah (fp16 LDS), GEMM2 (K=128,N=64), scale -> hb0 fp16.
// LDS: Wl 32KB (W1, then overlaid wh) + Al 17.0KB + Ah 17.0KB = 66.4KB -> 2 blk/CU.
__global__ __launch_bounds__(256) void fused_mlp_k(
    const __half* __restrict__ y,
    const int* __restrict__ rps, const int* __restrict__ rpe,
    const u16* __restrict__ adj,
    const float* __restrict__ W1, const float* __restrict__ b1,
    const float* __restrict__ wh, const float* __restrict__ ng,
    __half* __restrict__ hb0, int M)
{
    __shared__ __align__(16) float  Wl[8192];       // W1 (64x128) then wh (128x64)
    __shared__ __align__(16) float  Al[64 * 68];    // gathered agg, padded stride
    __shared__ __align__(16) __half Ah[64 * 136];   // relu'd t, fp16, padded stride

    const int tid = threadIdx.x;
    const int n0  = blockIdx.x << 6;

    // stage W1 (8192 floats) -- coalesced
    for (int i = tid; i < 2048; i += 256) st4(&Wl[4 * i], ld4(W1 + 4 * i));

    // gather: node = tid>>2 (0..63), q = tid&3 covers feats q*16..q*16+15
    {
        const int node = tid >> 2, q = tid & 3;
        const int gn = n0 + node;
        float4 A0 = make_float4(0.f, 0.f, 0.f, 0.f);
        float4 A1 = make_float4(0.f, 0.f, 0.f, 0.f);
        float4 A2 = make_float4(0.f, 0.f, 0.f, 0.f);
        float4 A3 = make_float4(0.f, 0.f, 0.f, 0.f);
        if (gn < M) {
            int e = rps[gn];
            const int e1 = rpe[gn];
            const __half* base = y + (q << 4);
            for (; e + 2 <= e1; e += 2) {
                const __half* ra = base + ((int)adj[e] << 6);
                const __half* rb = base + ((int)adj[e + 1] << 6);
                uint4 a0 = *reinterpret_cast<const uint4*>(ra);
                uint4 a1 = *reinterpret_cast<const uint4*>(ra + 8);
                uint4 b0 = *reinterpret_cast<const uint4*>(rb);
                uint4 b1v = *reinterpret_cast<const uint4*>(rb + 8);
                add_h8(A0, A1, a0); add_h8(A2, A3, a1);
                add_h8(A0, A1, b0); add_h8(A2, A3, b1v);
            }
            for (; e < e1; ++e) {
                const __half* ra = base + ((int)adj[e] << 6);
                uint4 a0 = *reinterpret_cast<const uint4*>(ra);
                uint4 a1 = *reinterpret_cast<const uint4*>(ra + 8);
                add_h8(A0, A1, a0); add_h8(A2, A3, a1);
            }
        }
        float* p = &Al[node * 68 + (q << 4)];
        st4(p, A0); st4(p + 4, A1); st4(p + 8, A2); st4(p + 12, A3);
    }
    __syncthreads();

    const int tr = tid & 15;
    const int tc = tid >> 4;
    float ngv[4];
#pragma unroll
    for (int i = 0; i < 4; ++i) {
        int gn = n0 + 4 * tr + i;
        ngv[i] = (gn < M) ? ng[gn] : 0.f;
    }

    // ---- GEMM1: t[64][128] = Al @ W1 ; thread -> nodes 4tr+i, cols tc*8..tc*8+7
    float acc1[4][8];
#pragma unroll
    for (int i = 0; i < 4; ++i)
#pragma unroll
        for (int j = 0; j < 8; ++j) acc1[i][j] = 0.f;
#pragma unroll 4
    for (int k = 0; k < 64; ++k) {
        float a0 = Al[(4 * tr + 0) * 68 + k];
        float a1 = Al[(4 * tr + 1) * 68 + k];
        float a2 = Al[(4 * tr + 2) * 68 + k];
        float a3 = Al[(4 * tr + 3) * 68 + k];
#pragma unroll
        for (int jq = 0; jq < 2; ++jq) {
            float4 w = ld4(&Wl[k * 128 + tc * 8 + 4 * jq]);
            acc1[0][4 * jq + 0] += a0 * w.x; acc1[0][4 * jq + 1] += a0 * w.y;
            acc1[0][4 * jq + 2] += a0 * w.z; acc1[0][4 * jq + 3] += a0 * w.w;
            acc1[1][4 * jq + 0] += a1 * w.x; acc1[1][4 * jq + 1] += a1 * w.y;
            acc1[1][4 * jq + 2] += a1 * w.z; acc1[1][4 * jq + 3] += a1 * w.w;
            acc1[2][4 * jq + 0] += a2 * w.x; acc1[2][4 * jq + 1] += a2 * w.y;
            acc1[2][4 * jq + 2] += a2 * w.z; acc1[2][4 * jq + 3] += a2 * w.w;
            acc1[3][4 * jq + 0] += a3 * w.x; acc1[3][4 * jq + 1] += a3 * w.y;
            acc1[3][4 * jq + 2] += a3 * w.z; acc1[3][4 * jq + 3] += a3 * w.w;
        }
    }
    __syncthreads();                 // all W1/Al reads done before overlay

    // relu(t*ng + b1) -> Ah (fp16); stage wh into Wl (overlays W1)
    {
        float4 bA = ld4(b1 + tc * 8);
        float4 bB = ld4(b1 + tc * 8 + 4);
#pragma unroll
        for (int i = 0; i < 4; ++i) {
            union { __half h[8]; uint4 u; } pk;
            float s = ngv[i];
            pk.h[0] = __float2half_rn(fmaxf(fmaf(acc1[i][0], s, bA.x), 0.f));
            pk.h[1] = __float2half_rn(fmaxf(fmaf(acc1[i][1], s, bA.y), 0.f));
            pk.h[2] = __float2half_rn(fmaxf(fmaf(acc1[i][2], s, bA.z), 0.f));
            pk.h[3] = __float2half_rn(fmaxf(fmaf(acc1[i][3], s, bA.w), 0.f));
            pk.h[4] = __float2half_rn(fmaxf(fmaf(acc1[i][4], s, bB.x), 0.f));
            pk.h[5] = __float2half_rn(fmaxf(fmaf(acc1[i][5], s, bB.y), 0.f));
            pk.h[6] = __float2half_rn(fmaxf(fmaf(acc1[i][6], s, bB.z), 0.f));
            pk.h[7] = __float2half_rn(fmaxf(fmaf(acc1[i][7], s, bB.w), 0.f));
            *reinterpret_cast<uint4*>(&Ah[(4 * tr + i) * 136 + tc * 8]) = pk.u;
        }
        for (int i = tid; i < 2048; i += 256) st4(&Wl[4 * i], ld4(wh + 4 * i));
    }
    __syncthreads();

    // ---- GEMM2: hb0[64][64] = relu_t @ wh ; thread -> nodes 4tr+i, cols tc*4..
    float acc2[4][4];
#pragma unroll
    for (int i = 0; i < 4; ++i)
#pragma unroll
        for (int j = 0; j < 4; ++j) acc2[i][j] = 0.f;
#pragma unroll 4
    for (int k = 0; k < 128; ++k) {
        float a0 = __half2float(Ah[(4 * tr + 0) * 136 + k]);
        float a1 = __half2float(Ah[(4 * tr + 1) * 136 + k]);
        float a2 = __half2float(Ah[(4 * tr + 2) * 136 + k]);
        float a3 = __half2float(Ah[(4 * tr + 3) * 136 + k]);
        float4 w = ld4(&Wl[k * 64 + tc * 4]);
        acc2[0][0] += a0 * w.x; acc2[0][1] += a0 * w.y;
        acc2[0][2] += a0 * w.z; acc2[0][3] += a0 * w.w;
        acc2[1][0] += a1 * w.x; acc2[1][1] += a1 * w.y;
        acc2[1][2] += a1 * w.z; acc2[1][3] += a1 * w.w;
        acc2[2][0] += a2 * w.x; acc2[2][1] += a2 * w.y;
        acc2[2][2] += a2 * w.z; acc2[2][3] += a2 * w.w;
        acc2[3][0] += a3 * w.x; acc2[3][1] += a3 * w.y;
        acc2[3][2] += a3 * w.z; acc2[3][3] += a3 * w.w;
    }
#pragma unroll
    for (int i = 0; i < 4; ++i) {
        int gn = n0 + 4 * tr + i;
        if (gn >= M) continue;
        float s = ngv[i];
        float4 o;
        o.x = acc2[i][0] * s; o.y = acc2[i][1] * s;
        o.z = acc2[i][2] * s; o.w = acc2[i][3] * s;
        st_h4(hb0 + (gn << 6) + tc * 4, o);
    }
}

// ---------- CSR row gather-sum, 8-lane group, half8 (16 B uint4) per lane ----------
static __device__ __forceinline__ void csr_row_sum_h8(
        const __half* __restrict__ tbl, const u16* __restrict__ adj,
        int e, int e1, int off, float4& A, float4& B) {
    for (; e + 4 <= e1; e += 4) {
        int s0 = adj[e], s1 = adj[e + 1], s2 = adj[e + 2], s3 = adj[e + 3];
        uint4 r0 = *reinterpret_cast<const uint4*>(tbl + (s0 << 6) + off);
        uint4 r1 = *reinterpret_cast<const uint4*>(tbl + (s1 << 6) + off);
        uint4 r2 = *reinterpret_cast<const uint4*>(tbl + (s2 << 6) + off);
        uint4 r3 = *reinterpret_cast<const uint4*>(tbl + (s3 << 6) + off);
        add_h8(A, B, r0); add_h8(A, B, r1); add_h8(A, B, r2); add_h8(A, B, r3);
    }
    for (; e < e1; ++e) {
        uint4 r = *reinterpret_cast<const uint4*>(tbl + (adj[e] << 6) + off);
        add_h8(A, B, r);
    }
}

// ---------- tiled fp32 GEMM (used for the skip branch only) ----------
template<int K, int N, int SMODE, int EPI, int OUT16>
__global__ __launch_bounds__(256) void gemm_k(
    const float* __restrict__ A, const float* __restrict__ A2,
    const float* __restrict__ W, const float* __restrict__ rs,
    const float* __restrict__ bias, void* __restrict__ outv, int M)
{
    constexpr int CPT = N / 16;
    constexpr int AS  = K + 1;
    constexpr int KQ  = K / 4;
    __shared__ __align__(16) float Wl[K * N];
    __shared__ __align__(16) float Al[64 * AS];

    const int tid = threadIdx.x;
    const int n0  = blockIdx.x << 6;

    for (int i = tid; i < K * N / 4; i += 256) st4(&Wl[4 * i], ld4(W + 4 * i));
    for (int i4 = tid; i4 < 64 * KQ; i4 += 256) {
        int n  = i4 / KQ;
        int k4 = (i4 & (KQ - 1)) << 2;
        int gn = n0 + n;
        float4 v = make_float4(0.f, 0.f, 0.f, 0.f);
        if (gn < M) {
            v = ld4(A + gn * K + k4);
            if (SMODE == 1) {
                float4 m4 = ld4(A2 + gn * K + k4);
                v.x *= m4.x; v.y *= m4.y; v.z *= m4.z; v.w *= m4.w;
            }
        }
        float* p = &Al[n * AS + k4];
        p[0] = v.x; p[1] = v.y; p[2] = v.z; p[3] = v.w;
    }
    __syncthreads();

    const int tr = tid & 15;
    const int tc = tid >> 4;

    float acc[4][CPT];
#pragma unroll
    for (int i = 0; i < 4; ++i)
#pragma unroll
        for (int j = 0; j < CPT; ++j) acc[i][j] = 0.f;

#pragma unroll 4
    for (int k = 0; k < K; ++k) {
        float a0 = Al[(4 * tr + 0) * AS + k];
        float a1 = Al[(4 * tr + 1) * AS + k];
        float a2 = Al[(4 * tr + 2) * AS + k];
        float a3 = Al[(4 * tr + 3) * AS + k];
#pragma unroll
        for (int jq = 0; jq < CPT / 4; ++jq) {
            float4 w = ld4(&Wl[k * N + tc * CPT + 4 * jq]);
            acc[0][4 * jq + 0] += a0 * w.x; acc[0][4 * jq + 1] += a0 * w.y;
            acc[0][4 * jq + 2] += a0 * w.z; acc[0][4 * jq + 3] += a0 * w.w;
            acc[1][4 * jq + 0] += a1 * w.x; acc[1][4 * jq + 1] += a1 * w.y;
            acc[1][4 * jq + 2] += a1 * w.z; acc[1][4 * jq + 3] += a1 * w.w;
            acc[2][4 * jq + 0] += a2 * w.x; acc[2][4 * jq + 1] += a2 * w.y;
            acc[2][4 * jq + 2] += a2 * w.z; acc[2][4 * jq + 3] += a2 * w.w;
            acc[3][4 * jq + 0] += a3 * w.x; acc[3][4 * jq + 1] += a3 * w.y;
            acc[3][4 * jq + 2] += a3 * w.z; acc[3][4 * jq + 3] += a3 * w.w;
        }
    }

#pragma unroll
    for (int i = 0; i < 4; ++i) {
        int gn = n0 + 4 * tr + i;
        if (gn >= M) continue;
        float s = rs[gn];
#pragma unroll
        for (int jq = 0; jq < CPT / 4; ++jq) {
            float4 o;
            if (EPI == 1) {
                float4 b4 = ld4(bias + tc * CPT + 4 * jq);
                o.x = fmaxf(fmaf(acc[i][4 * jq + 0], s, b4.x), 0.f);
                o.y = fmaxf(fmaf(acc[i][4 * jq + 1], s, b4.y), 0.f);
                o.z = fmaxf(fmaf(acc[i][4 * jq + 2], s, b4.z), 0.f);
                o.w = fmaxf(fmaf(acc[i][4 * jq + 3], s, b4.w), 0.f);
            } else {
                o.x = acc[i][4 * jq + 0] * s; o.y = acc[i][4 * jq + 1] * s;
                o.z = acc[i][4 * jq + 2] * s; o.w = acc[i][4 * jq + 3] * s;
            }
            if (OUT16) {
                st_h4((__half*)outv + gn * N + tc * CPT + 4 * jq, o);
            } else {
                st4((float*)outv + gn * N + tc * CPT + 4 * jq, o);
            }
        }
    }
}

// ---------- fused final: two fp16 CSR aggs + bias + sigmoid; 32 nodes/block ----------
__global__ __launch_bounds__(256) void final2_k(
    const __half* __restrict__ hb, const __half* __restrict__ sb,
    const int* __restrict__ rps_g, const int* __restrict__ rpe_g,
    const u16* __restrict__ adj_g,
    const int* __restrict__ rps_f, const int* __restrict__ rpe_f,
    const u16* __restrict__ adj_f,
    const float* __restrict__ ng, const float* __restrict__ nf,
    const float* __restrict__ bh, const float* __restrict__ bs,
    float* __restrict__ out)
{
    const int tid = threadIdx.x;
    const int fl = tid & 7;
    const int n  = blockIdx.x * 32 + (tid >> 3);
    if (n >= N_NODES) return;
    const int off = fl << 3;
    float4 Ag = make_float4(0.f, 0.f, 0.f, 0.f);
    float4 Bg = make_float4(0.f, 0.f, 0.f, 0.f);
    float4 Af = make_float4(0.f, 0.f, 0.f, 0.f);
    float4 Bf = make_float4(0.f, 0.f, 0.f, 0.f);
    csr_row_sum_h8(hb, adj_g, rps_g[n], rpe_g[n], off, Ag, Bg);
    csr_row_sum_h8(sb, adj_f, rps_f[n], rpe_f[n], off, Af, Bf);
    const float g = ng[n], f = nf[n];
    float4 b0 = ld4(bh + off), b1 = ld4(bh + off + 4);
    float4 s0 = ld4(bs + off), s1 = ld4(bs + off + 4);
    float4 o0, o1;
    float t;
    t = Ag.x * g + b0.x + Af.x * f + s0.x; o0.x = 1.f / (1.f + expf(-t));
    t = Ag.y * g + b0.y + Af.y * f + s0.y; o0.y = 1.f / (1.f + expf(-t));
    t = Ag.z * g + b0.z + Af.z * f + s0.z; o0.z = 1.f / (1.f + expf(-t));
    t = Ag.w * g + b0.w + Af.w * f + s0.w; o0.w = 1.f / (1.f + expf(-t));
    t = Bg.x * g + b1.x + Bf.x * f + s1.x; o1.x = 1.f / (1.f + expf(-t));
    t = Bg.y * g + b1.y + Bf.y * f + s1.y; o1.y = 1.f / (1.f + expf(-t));
    t = Bg.z * g + b1.z + Bf.z * f + s1.z; o1.z = 1.f / (1.f + expf(-t));
    t = Bg.w * g + b1.w + Bf.w * f + s1.w; o1.w = 1.f / (1.f + expf(-t));
    st4(out + (n << 6) + off, o0);
    st4(out + (n << 6) + off + 4, o1);
}

extern "C" void kernel_launch(void* const* d_in, const int* in_sizes, int n_in,
                              void* d_out, int out_size, void* d_ws, size_t ws_size,
                              hipStream_t stream) {
    const float* features = (const float*)d_in[0];
    const float* mask     = (const float*)d_in[1];
    const float* norm_g   = (const float*)d_in[2];
    const float* norm_f   = (const float*)d_in[3];
    const int*   src_g    = (const int*)d_in[4];
    const int*   dst_g    = (const int*)d_in[5];
    const int*   src_f    = (const int*)d_in[6];
    const int*   dst_f    = (const int*)d_in[7];
    const float* W1  = (const float*)d_in[8];
    const float* b1  = (const float*)d_in[9];
    const float* wh  = (const float*)d_in[10];
    const float* bh  = (const float*)d_in[11];
    const float* wsw = (const float*)d_in[12];
    const float* bs  = (const float*)d_in[13];
    float* out = (float*)d_out;
    float* ws  = (float*)d_ws;

    // ---- workspace layout (float-unit offsets) ----
    //   [0    , 1.6M)  y   fp16 (live through fused_mlp + final gather source? no:
    //                   y dead after fused_mlp; distinct from hb0 since fused_mlp
    //                   reads y[src] of ANY node while writing hb0)
    //   [1.6M , 3.2M)  hb0 fp16
    //   [3.2M , 4.8M)  sb0 fp16
    //   [6.4M ,12.8M)  rec_g/rec_f/bukcur build scratch (dead after P3)
    // persistent at [12.8M): rps/rpe x2 graphs, adj_g/adj_f (CAPB-padded)
    __half* y   = (__half*)ws;
    __half* hb0 = (__half*)(ws + 1600000);
    __half* sb0 = (__half*)(ws + 3200000);
    int* creg   = (int*)(ws + 6400000);
    u32* rec_g  = (u32*)creg;                  // NBUK*CAPB = 1204224
    u32* rec_f  = rec_g + NBUK * CAPB;
    int* bukcur = (int*)(rec_f + NBUK * CAPB); // 196 ints
    int* pers   = (int*)(ws + 12800000);
    int* rps_g  = pers;                        // 50000
    int* rpe_g  = pers + 50000;                // 50000
    int* rps_f  = pers + 100000;               // 50000
    int* rpe_f  = pers + 150000;               // 50000
    u16* adj_g  = (u16*)(pers + 200000);       // NBUK*CAPB u16
    u16* adj_f  = adj_g + NBUK * CAPB;

    const int gblocks = (N_NODES + 63) / 64;   // 782
    const int nblk32  = (N_NODES + 31) / 32;   // 1563

    // CSR build: reserve-based bucket partition (no global scan)
    hipMemsetAsync(bukcur, 0, 2 * NBUK * sizeof(int), stream);
    part_k<<<2 * NBLK, 256, 0, stream>>>(src_g, dst_g, rec_g,
                                         src_f, dst_f, rec_f, bukcur,
                                         features, mask, norm_g, y);
    p3_build_k<<<2 * NBUK, 512, 0, stream>>>(rec_g, rps_g, rpe_g, adj_g,
                                             rec_f, rps_f, rpe_f, adj_f, bukcur);

    // hb0 = fp16( ng * (relu( aggG(y)@W1 * ng + b1 ) @ wh) )   -- one kernel
    fused_mlp_k<<<gblocks, 256, 0, stream>>>(y, rps_g, rpe_g, adj_g,
                                             W1, b1, wh, norm_g, hb0, N_NODES);

    // sb0 = ((features*mask)@ws)*nf   (fp16 out)
    gemm_k<64, 64, 1, 2, 1><<<gblocks, 256, 0, stream>>>(features, mask, wsw, norm_f,
                                                         nullptr, (void*)sb0, N_NODES);

    // out = sigmoid(aggG(hb0)*ng + bh + aggF(sb0)*nf + bs)
    final2_k<<<nblk32, 256, 0, stream>>>(hb0, sb0, rps_g, rpe_g, adj_g,
                                         rps_f, rpe_f, adj_f,
                                         norm_g, norm_f, bh, bs, out);
}

// Round 11
// 238.504 us; speedup vs baseline: 1.0483x; 1.0483x over previous
//
#include <hip/hip_runtime.h>
#include <hip/hip_fp16.h>

#define N_NODES 50000
#define N_EDGES 800000
#define IN_F 64
#define H_F 128
#define NBUK 98          // node buckets of 512: bucket = dst >> 9
#define CAPB 12288       // fixed per-bucket record capacity (mean 8163, +45 sigma)
#define EPB 2048         // edges per block in part_k
#define NBLK 391         // ceil(N_EDGES / EPB)

typedef unsigned short u16;
typedef unsigned int u32;

static __device__ __forceinline__ float4 ld4(const float* p) {
    return *reinterpret_cast<const float4*>(p);
}
static __device__ __forceinline__ void st4(float* p, float4 v) {
    *reinterpret_cast<float4*>(p) = v;
}
// pack float4 -> 4 fp16 (8 B store)
static __device__ __forceinline__ void st_h4(__half* p, float4 v) {
    union { __half h[4]; uint2 u; } pk;
    pk.h[0] = __float2half_rn(v.x);
    pk.h[1] = __float2half_rn(v.y);
    pk.h[2] = __float2half_rn(v.z);
    pk.h[3] = __float2half_rn(v.w);
    *reinterpret_cast<uint2*>(p) = pk.u;
}
// acc(8 floats in two float4) += 8 halfs packed in uint4
static __device__ __forceinline__ void add_h8(float4& a, float4& b, uint4 r) {
    __half2* p = reinterpret_cast<__half2*>(&r);
    float2 f0 = __half22float2(p[0]);
    float2 f1 = __half22float2(p[1]);
    float2 f2 = __half22float2(p[2]);
    float2 f3 = __half22float2(p[3]);
    a.x += f0.x; a.y += f0.y; a.z += f1.x; a.w += f1.y;
    b.x += f2.x; b.y += f2.y; b.z += f3.x; b.w += f3.y;
}
// unpack 8 fp16 (uint4) -> 8 floats
static __device__ __forceinline__ void unpack8(uint4 u, float* w) {
    const __half2* hp = reinterpret_cast<const __half2*>(&u);
    float2 f0 = __half22float2(hp[0]);
    float2 f1 = __half22float2(hp[1]);
    float2 f2 = __half22float2(hp[2]);
    float2 f3 = __half22float2(hp[3]);
    w[0] = f0.x; w[1] = f0.y; w[2] = f1.x; w[3] = f1.y;
    w[4] = f2.x; w[5] = f2.y; w[6] = f3.x; w[7] = f3.y;
}

// ---------- part_k: single-pass bucket partition (both graphs) + fused y = f*m*ng
__global__ __launch_bounds__(256) void part_k(
    const int* __restrict__ src_g, const int* __restrict__ dst_g, u32* __restrict__ rec_g,
    const int* __restrict__ src_f, const int* __restrict__ dst_f, u32* __restrict__ rec_f,
    int* __restrict__ bukcur,
    const float* __restrict__ f, const float* __restrict__ m,
    const float* __restrict__ ng, __half* __restrict__ y)
{
    __shared__ int c[NBUK];
    __shared__ int base[NBUK];
    const int tid = threadIdx.x;
    const int graph = blockIdx.x >= NBLK;
    const int blk = blockIdx.x - graph * NBLK;
    const int* src = graph ? src_f : src_g;
    const int* dst = graph ? dst_f : dst_g;
    u32* rec = graph ? rec_f : rec_g;
    int* cur = bukcur + graph * NBUK;

    if (tid < NBUK) c[tid] = 0;
    __syncthreads();
    const int e0 = blk * EPB;
    const int e1 = min(e0 + EPB, N_EDGES);

    u32 r_[8];
    bool v_[8];
#pragma unroll
    for (int j = 0; j < 8; ++j) {
        int e = e0 + tid + j * 256;
        v_[j] = (e < e1);
        int d = 0, s = 0;
        if (v_[j]) { d = dst[e]; s = src[e]; }
        r_[j] = ((u32)s << 16) | (u32)d;
        if (v_[j]) atomicAdd(&c[d >> 9], 1);
    }
    __syncthreads();
    if (tid < NBUK) base[tid] = atomicAdd(&cur[tid], c[tid]);
    __syncthreads();
    if (tid < NBUK) c[tid] = 0;                   // reuse as local cursor
    __syncthreads();
#pragma unroll
    for (int j = 0; j < 8; ++j) {
        if (v_[j]) {
            u32 r = r_[j];
            int b = (int)((r & 0xFFFFu) >> 9);
            int p = base[b] + atomicAdd(&c[b], 1);
            if (p < CAPB) rec[b * CAPB + p] = r;  // guard: drop on (impossible) overflow
        }
    }
    // fused: y = features * mask * ng, stored fp16
    for (int i = blockIdx.x * 256 + tid; i < N_NODES * (IN_F / 4);
         i += gridDim.x * 256) {
        int n = i >> 4;
        float s = ng[n];
        float4 a = ld4(f + 4 * i);
        float4 b = ld4(m + 4 * i);
        float4 r;
        r.x = a.x * b.x * s; r.y = a.y * b.y * s;
        r.z = a.z * b.z * s; r.w = a.w * b.w * s;
        st_h4(y + 4 * i, r);
    }
}

// ---------- P3: per-bucket LDS hist + scan -> rps/rpe; LDS-cursor scatter -> adj
__global__ __launch_bounds__(512) void p3_build_k(
    const u32* __restrict__ rec_g, int* __restrict__ rps_g, int* __restrict__ rpe_g,
    u16* __restrict__ adj_g,
    const u32* __restrict__ rec_f, int* __restrict__ rps_f, int* __restrict__ rpe_f,
    u16* __restrict__ adj_f,
    const int* __restrict__ bukcur)
{
    __shared__ int hist[512];
    __shared__ int tmp[512];
    const int tid = threadIdx.x;
    const int graph = blockIdx.x >= NBUK;
    const int b = blockIdx.x - graph * NBUK;
    const u32* rec = graph ? rec_f : rec_g;
    int* rps = graph ? rps_f : rps_g;
    int* rpe = graph ? rpe_f : rpe_g;
    u16* adj = graph ? adj_f : adj_g;
    const int e_base = b * CAPB;
    const int e_cnt  = min(bukcur[graph * NBUK + b], CAPB);

    hist[tid] = 0;
    __syncthreads();
    for (int i = tid; i < e_cnt; i += 512)
        atomicAdd(&hist[rec[e_base + i] & 511], 1);
    __syncthreads();
    const int v = hist[tid];
    tmp[tid] = v;
    __syncthreads();
    for (int o = 1; o < 512; o <<= 1) {
        int t = (tid >= o) ? tmp[tid - o] : 0;
        __syncthreads();
        tmp[tid] += t;
        __syncthreads();
    }
    const int incl = tmp[tid];
    const int excl = incl - v;
    const int n = (b << 9) + tid;
    if (n < N_NODES) {
        rps[n] = e_base + excl;
        rpe[n] = e_base + incl;
    }
    hist[tid] = excl;                             // becomes cursor
    __syncthreads();
    for (int i = tid; i < e_cnt; i += 512) {
        u32 r = rec[e_base + i];
        int p = atomicAdd(&hist[r & 511], 1);
        adj[e_base + p] = (u16)(r >> 16);
    }
}

// ---------- fused MLP: hb0 = fp16( ng * (relu( aggG(y)@W1 * ng + b1 ) @ wh) ) ----
// v2: fp16 weights in LDS (16KB, overlaid W1->wh), Al stride 65 (2-way, free),
// Ah stride 130 halfs (=65 words, free), GEMM2 A-reads as u32 pairs.
// LDS: 16K + 16.64K + 16.64K = 49.3KB -> 3 blocks/CU (12 waves/CU).
__global__ __launch_bounds__(256) void fused_mlp_k(
    const __half* __restrict__ y,
    const int* __restrict__ rps, const int* __restrict__ rpe,
    const u16* __restrict__ adj,
    const float* __restrict__ W1, const float* __restrict__ b1,
    const float* __restrict__ wh, const float* __restrict__ ng,
    __half* __restrict__ hb0, int M)
{
    __shared__ __align__(16) __half WlH[8192];      // W1 (64x128) fp16, then wh (128x64)
    __shared__ __align__(16) float  Al[64 * 65];    // gathered agg, stride 65
    __shared__ __align__(16) __half Ah[64 * 130];   // relu'd t fp16, stride 130

    const int tid = threadIdx.x;
    const int n0  = blockIdx.x << 6;

    // stage W1 fp32 -> fp16 LDS
    for (int i = tid; i < 2048; i += 256) st_h4(&WlH[4 * i], ld4(W1 + 4 * i));

    // gather: node = tid>>2 (0..63), q = tid&3 covers feats q*16..q*16+15
    {
        const int node = tid >> 2, q = tid & 3;
        const int gn = n0 + node;
        float4 A0 = make_float4(0.f, 0.f, 0.f, 0.f);
        float4 A1 = make_float4(0.f, 0.f, 0.f, 0.f);
        float4 A2 = make_float4(0.f, 0.f, 0.f, 0.f);
        float4 A3 = make_float4(0.f, 0.f, 0.f, 0.f);
        if (gn < M) {
            int e = rps[gn];
            const int e1 = rpe[gn];
            const __half* base = y + (q << 4);
            for (; e + 2 <= e1; e += 2) {
                const __half* ra = base + ((int)adj[e] << 6);
                const __half* rb = base + ((int)adj[e + 1] << 6);
                uint4 a0 = *reinterpret_cast<const uint4*>(ra);
                uint4 a1 = *reinterpret_cast<const uint4*>(ra + 8);
                uint4 b0 = *reinterpret_cast<const uint4*>(rb);
                uint4 b1v = *reinterpret_cast<const uint4*>(rb + 8);
                add_h8(A0, A1, a0); add_h8(A2, A3, a1);
                add_h8(A0, A1, b0); add_h8(A2, A3, b1v);
            }
            for (; e < e1; ++e) {
                const __half* ra = base + ((int)adj[e] << 6);
                uint4 a0 = *reinterpret_cast<const uint4*>(ra);
                uint4 a1 = *reinterpret_cast<const uint4*>(ra + 8);
                add_h8(A0, A1, a0); add_h8(A2, A3, a1);
            }
        }
        float* p = &Al[node * 65 + (q << 4)];      // scalar stores: stride-65 rows
        p[0]  = A0.x; p[1]  = A0.y; p[2]  = A0.z; p[3]  = A0.w;
        p[4]  = A1.x; p[5]  = A1.y; p[6]  = A1.z; p[7]  = A1.w;
        p[8]  = A2.x; p[9]  = A2.y; p[10] = A2.z; p[11] = A2.w;
        p[12] = A3.x; p[13] = A3.y; p[14] = A3.z; p[15] = A3.w;
    }
    __syncthreads();

    const int tr = tid & 15;
    const int tc = tid >> 4;
    float ngv[4];
#pragma unroll
    for (int i = 0; i < 4; ++i) {
        int gn = n0 + 4 * tr + i;
        ngv[i] = (gn < M) ? ng[gn] : 0.f;
    }

    // ---- GEMM1: t[64][128] = Al @ W1 ; thread -> nodes 4tr+i, cols tc*8..tc*8+7
    float acc1[4][8];
#pragma unroll
    for (int i = 0; i < 4; ++i)
#pragma unroll
        for (int j = 0; j < 8; ++j) acc1[i][j] = 0.f;
#pragma unroll 4
    for (int k = 0; k < 64; ++k) {
        float a0 = Al[(4 * tr + 0) * 65 + k];
        float a1 = Al[(4 * tr + 1) * 65 + k];
        float a2 = Al[(4 * tr + 2) * 65 + k];
        float a3 = Al[(4 * tr + 3) * 65 + k];
        uint4 wu = *reinterpret_cast<const uint4*>(&WlH[k * 128 + tc * 8]);
        float wv[8];
        unpack8(wu, wv);
#pragma unroll
        for (int j = 0; j < 8; ++j) {
            acc1[0][j] += a0 * wv[j];
            acc1[1][j] += a1 * wv[j];
            acc1[2][j] += a2 * wv[j];
            acc1[3][j] += a3 * wv[j];
        }
    }
    __syncthreads();                 // all W1/Al reads done before overlay

    // relu(t*ng + b1) -> Ah (fp16, u32 stores); stage wh (fp16) overlaying W1
    {
        float4 bA = ld4(b1 + tc * 8);
        float4 bB = ld4(b1 + tc * 8 + 4);
#pragma unroll
        for (int i = 0; i < 4; ++i) {
            union { __half h[8]; u32 w[4]; } pk;
            float s = ngv[i];
            pk.h[0] = __float2half_rn(fmaxf(fmaf(acc1[i][0], s, bA.x), 0.f));
            pk.h[1] = __float2half_rn(fmaxf(fmaf(acc1[i][1], s, bA.y), 0.f));
            pk.h[2] = __float2half_rn(fmaxf(fmaf(acc1[i][2], s, bA.z), 0.f));
            pk.h[3] = __float2half_rn(fmaxf(fmaf(acc1[i][3], s, bA.w), 0.f));
            pk.h[4] = __float2half_rn(fmaxf(fmaf(acc1[i][4], s, bB.x), 0.f));
            pk.h[5] = __float2half_rn(fmaxf(fmaf(acc1[i][5], s, bB.y), 0.f));
            pk.h[6] = __float2half_rn(fmaxf(fmaf(acc1[i][6], s, bB.z), 0.f));
            pk.h[7] = __float2half_rn(fmaxf(fmaf(acc1[i][7], s, bB.w), 0.f));
            u32* dst = reinterpret_cast<u32*>(&Ah[(4 * tr + i) * 130 + tc * 8]);
            dst[0] = pk.w[0]; dst[1] = pk.w[1]; dst[2] = pk.w[2]; dst[3] = pk.w[3];
        }
        for (int i = tid; i < 2048; i += 256) st_h4(&WlH[4 * i], ld4(wh + 4 * i));
    }
    __syncthreads();

    // ---- GEMM2: hb0[64][64] = relu_t @ wh ; u32 A-reads (2 k per iter)
    float acc2[4][4];
#pragma unroll
    for (int i = 0; i < 4; ++i)
#pragma unroll
        for (int j = 0; j < 4; ++j) acc2[i][j] = 0.f;
#pragma unroll 4
    for (int k2 = 0; k2 < 64; ++k2) {
        u32 a0u = *reinterpret_cast<const u32*>(&Ah[(4 * tr + 0) * 130 + 2 * k2]);
        u32 a1u = *reinterpret_cast<const u32*>(&Ah[(4 * tr + 1) * 130 + 2 * k2]);
        u32 a2u = *reinterpret_cast<const u32*>(&Ah[(4 * tr + 2) * 130 + 2 * k2]);
        u32 a3u = *reinterpret_cast<const u32*>(&Ah[(4 * tr + 3) * 130 + 2 * k2]);
        float2 a0 = __half22float2(*reinterpret_cast<const __half2*>(&a0u));
        float2 a1 = __half22float2(*reinterpret_cast<const __half2*>(&a1u));
        float2 a2 = __half22float2(*reinterpret_cast<const __half2*>(&a2u));
        float2 a3 = __half22float2(*reinterpret_cast<const __half2*>(&a3u));
        uint2 wau = *reinterpret_cast<const uint2*>(&WlH[(2 * k2) * 64 + tc * 4]);
        uint2 wbu = *reinterpret_cast<const uint2*>(&WlH[(2 * k2 + 1) * 64 + tc * 4]);
        const __half2* wap = reinterpret_cast<const __half2*>(&wau);
        const __half2* wbp = reinterpret_cast<const __half2*>(&wbu);
        float2 wa0 = __half22float2(wap[0]), wa1 = __half22float2(wap[1]);
        float2 wb0 = __half22float2(wbp[0]), wb1 = __half22float2(wbp[1]);
        float wva[4] = { wa0.x, wa0.y, wa1.x, wa1.y };
        float wvb[4] = { wb0.x, wb0.y, wb1.x, wb1.y };
#pragma unroll
        for (int j = 0; j < 4; ++j) {
            acc2[0][j] += a0.x * wva[j] + a0.y * wvb[j];
            acc2[1][j] += a1.x * wva[j] + a1.y * wvb[j];
            acc2[2][j] += a2.x * wva[j] + a2.y * wvb[j];
            acc2[3][j] += a3.x * wva[j] + a3.y * wvb[j];
        }
    }
#pragma unroll
    for (int i = 0; i < 4; ++i) {
        int gn = n0 + 4 * tr + i;
        if (gn >= M) continue;
        float s = ngv[i];
        float4 o;
        o.x = acc2[i][0] * s; o.y = acc2[i][1] * s;
        o.z = acc2[i][2] * s; o.w = acc2[i][3] * s;
        st_h4(hb0 + (gn << 6) + tc * 4, o);
    }
}

// ---------- CSR row gather-sum, 8-lane group, half8 (16 B uint4) per lane ----------
static __device__ __forceinline__ void csr_row_sum_h8(
        const __half* __restrict__ tbl, const u16* __restrict__ adj,
        int e, int e1, int off, float4& A, float4& B) {
    for (; e + 4 <= e1; e += 4) {
        int s0 = adj[e], s1 = adj[e + 1], s2 = adj[e + 2], s3 = adj[e + 3];
        uint4 r0 = *reinterpret_cast<const uint4*>(tbl + (s0 << 6) + off);
        uint4 r1 = *reinterpret_cast<const uint4*>(tbl + (s1 << 6) + off);
        uint4 r2 = *reinterpret_cast<const uint4*>(tbl + (s2 << 6) + off);
        uint4 r3 = *reinterpret_cast<const uint4*>(tbl + (s3 << 6) + off);
        add_h8(A, B, r0); add_h8(A, B, r1); add_h8(A, B, r2); add_h8(A, B, r3);
    }
    for (; e < e1; ++e) {
        uint4 r = *reinterpret_cast<const uint4*>(tbl + (adj[e] << 6) + off);
        add_h8(A, B, r);
    }
}

// ---------- tiled fp32 GEMM (used for the skip branch only) ----------
template<int K, int N, int SMODE, int EPI, int OUT16>
__global__ __launch_bounds__(256) void gemm_k(
    const float* __restrict__ A, const float* __restrict__ A2,
    const float* __restrict__ W, const float* __restrict__ rs,
    const float* __restrict__ bias, void* __restrict__ outv, int M)
{
    constexpr int CPT = N / 16;
    constexpr int AS  = K + 1;
    constexpr int KQ  = K / 4;
    __shared__ __align__(16) float Wl[K * N];
    __shared__ __align__(16) float Al[64 * AS];

    const int tid = threadIdx.x;
    const int n0  = blockIdx.x << 6;

    for (int i = tid; i < K * N / 4; i += 256) st4(&Wl[4 * i], ld4(W + 4 * i));
    for (int i4 = tid; i4 < 64 * KQ; i4 += 256) {
        int n  = i4 / KQ;
        int k4 = (i4 & (KQ - 1)) << 2;
        int gn = n0 + n;
        float4 v = make_float4(0.f, 0.f, 0.f, 0.f);
        if (gn < M) {
            v = ld4(A + gn * K + k4);
            if (SMODE == 1) {
                float4 m4 = ld4(A2 + gn * K + k4);
                v.x *= m4.x; v.y *= m4.y; v.z *= m4.z; v.w *= m4.w;
            }
        }
        float* p = &Al[n * AS + k4];
        p[0] = v.x; p[1] = v.y; p[2] = v.z; p[3] = v.w;
    }
    __syncthreads();

    const int tr = tid & 15;
    const int tc = tid >> 4;

    float acc[4][CPT];
#pragma unroll
    for (int i = 0; i < 4; ++i)
#pragma unroll
        for (int j = 0; j < CPT; ++j) acc[i][j] = 0.f;

#pragma unroll 4
    for (int k = 0; k < K; ++k) {
        float a0 = Al[(4 * tr + 0) * AS + k];
        float a1 = Al[(4 * tr + 1) * AS + k];
        float a2 = Al[(4 * tr + 2) * AS + k];
        float a3 = Al[(4 * tr + 3) * AS + k];
#pragma unroll
        for (int jq = 0; jq < CPT / 4; ++jq) {
            float4 w = ld4(&Wl[k * N + tc * CPT + 4 * jq]);
            acc[0][4 * jq + 0] += a0 * w.x; acc[0][4 * jq + 1] += a0 * w.y;
            acc[0][4 * jq + 2] += a0 * w.z; acc[0][4 * jq + 3] += a0 * w.w;
            acc[1][4 * jq + 0] += a1 * w.x; acc[1][4 * jq + 1] += a1 * w.y;
            acc[1][4 * jq + 2] += a1 * w.z; acc[1][4 * jq + 3] += a1 * w.w;
            acc[2][4 * jq + 0] += a2 * w.x; acc[2][4 * jq + 1] += a2 * w.y;
            acc[2][4 * jq + 2] += a2 * w.z; acc[2][4 * jq + 3] += a2 * w.w;
            acc[3][4 * jq + 0] += a3 * w.x; acc[3][4 * jq + 1] += a3 * w.y;
            acc[3][4 * jq + 2] += a3 * w.z; acc[3][4 * jq + 3] += a3 * w.w;
        }
    }

#pragma unroll
    for (int i = 0; i < 4; ++i) {
        int gn = n0 + 4 * tr + i;
        if (gn >= M) continue;
        float s = rs[gn];
#pragma unroll
        for (int jq = 0; jq < CPT / 4; ++jq) {
            float4 o;
            if (EPI == 1) {
                float4 b4 = ld4(bias + tc * CPT + 4 * jq);
                o.x = fmaxf(fmaf(acc[i][4 * jq + 0], s, b4.x), 0.f);
                o.y = fmaxf(fmaf(acc[i][4 * jq + 1], s, b4.y), 0.f);
                o.z = fmaxf(fmaf(acc[i][4 * jq + 2], s, b4.z), 0.f);
                o.w = fmaxf(fmaf(acc[i][4 * jq + 3], s, b4.w), 0.f);
            } else {
                o.x = acc[i][4 * jq + 0] * s; o.y = acc[i][4 * jq + 1] * s;
                o.z = acc[i][4 * jq + 2] * s; o.w = acc[i][4 * jq + 3] * s;
            }
            if (OUT16) {
                st_h4((__half*)outv + gn * N + tc * CPT + 4 * jq, o);
            } else {
                st4((float*)outv + gn * N + tc * CPT + 4 * jq, o);
            }
        }
    }
}

// ---------- fused final: two fp16 CSR aggs + bias + sigmoid; 32 nodes/block ----------
__global__ __launch_bounds__(256) void final2_k(
    const __half* __restrict__ hb, const __half* __restrict__ sb,
    const int* __restrict__ rps_g, const int* __restrict__ rpe_g,
    const u16* __restrict__ adj_g,
    const int* __restrict__ rps_f, const int* __restrict__ rpe_f,
    const u16* __restrict__ adj_f,
    const float* __restrict__ ng, const float* __restrict__ nf,
    const float* __restrict__ bh, const float* __restrict__ bs,
    float* __restrict__ out)
{
    const int tid = threadIdx.x;
    const int fl = tid & 7;
    const int n  = blockIdx.x * 32 + (tid >> 3);
    if (n >= N_NODES) return;
    const int off = fl << 3;
    float4 Ag = make_float4(0.f, 0.f, 0.f, 0.f);
    float4 Bg = make_float4(0.f, 0.f, 0.f, 0.f);
    float4 Af = make_float4(0.f, 0.f, 0.f, 0.f);
    float4 Bf = make_float4(0.f, 0.f, 0.f, 0.f);
    csr_row_sum_h8(hb, adj_g, rps_g[n], rpe_g[n], off, Ag, Bg);
    csr_row_sum_h8(sb, adj_f, rps_f[n], rpe_f[n], off, Af, Bf);
    const float g = ng[n], f = nf[n];
    float4 b0 = ld4(bh + off), b1 = ld4(bh + off + 4);
    float4 s0 = ld4(bs + off), s1 = ld4(bs + off + 4);
    float4 o0, o1;
    float t;
    t = Ag.x * g + b0.x + Af.x * f + s0.x; o0.x = 1.f / (1.f + expf(-t));
    t = Ag.y * g + b0.y + Af.y * f + s0.y; o0.y = 1.f / (1.f + expf(-t));
    t = Ag.z * g + b0.z + Af.z * f + s0.z; o0.z = 1.f / (1.f + expf(-t));
    t = Ag.w * g + b0.w + Af.w * f + s0.w; o0.w = 1.f / (1.f + expf(-t));
    t = Bg.x * g + b1.x + Bf.x * f + s1.x; o1.x = 1.f / (1.f + expf(-t));
    t = Bg.y * g + b1.y + Bf.y * f + s1.y; o1.y = 1.f / (1.f + expf(-t));
    t = Bg.z * g + b1.z + Bf.z * f + s1.z; o1.z = 1.f / (1.f + expf(-t));
    t = Bg.w * g + b1.w + Bf.w * f + s1.w; o1.w = 1.f / (1.f + expf(-t));
    st4(out + (n << 6) + off, o0);
    st4(out + (n << 6) + off + 4, o1);
}

extern "C" void kernel_launch(void* const* d_in, const int* in_sizes, int n_in,
                              void* d_out, int out_size, void* d_ws, size_t ws_size,
                              hipStream_t stream) {
    const float* features = (const float*)d_in[0];
    const float* mask     = (const float*)d_in[1];
    const float* norm_g   = (const float*)d_in[2];
    const float* norm_f   = (const float*)d_in[3];
    const int*   src_g    = (const int*)d_in[4];
    const int*   dst_g    = (const int*)d_in[5];
    const int*   src_f    = (const int*)d_in[6];
    const int*   dst_f    = (const int*)d_in[7];
    const float* W1  = (const float*)d_in[8];
    const float* b1  = (const float*)d_in[9];
    const float* wh  = (const float*)d_in[10];
    const float* bh  = (const float*)d_in[11];
    const float* wsw = (const float*)d_in[12];
    const float* bs  = (const float*)d_in[13];
    float* out = (float*)d_out;
    float* ws  = (float*)d_ws;

    // ---- workspace layout (float-unit offsets) ----
    //   [0    , 1.6M)  y   fp16  (dead after fused_mlp)
    //   [1.6M , 3.2M)  hb0 fp16
    //   [3.2M , 4.8M)  sb0 fp16
    //   [6.4M ,12.8M)  rec_g/rec_f/bukcur build scratch (dead after P3)
    // persistent at [12.8M): rps/rpe x2 graphs, adj_g/adj_f (CAPB-padded)
    __half* y   = (__half*)ws;
    __half* hb0 = (__half*)(ws + 1600000);
    __half* sb0 = (__half*)(ws + 3200000);
    int* creg   = (int*)(ws + 6400000);
    u32* rec_g  = (u32*)creg;                  // NBUK*CAPB = 1204224
    u32* rec_f  = rec_g + NBUK * CAPB;
    int* bukcur = (int*)(rec_f + NBUK * CAPB); // 196 ints
    int* pers   = (int*)(ws + 12800000);
    int* rps_g  = pers;                        // 50000
    int* rpe_g  = pers + 50000;                // 50000
    int* rps_f  = pers + 100000;               // 50000
    int* rpe_f  = pers + 150000;               // 50000
    u16* adj_g  = (u16*)(pers + 200000);       // NBUK*CAPB u16
    u16* adj_f  = adj_g + NBUK * CAPB;

    const int gblocks = (N_NODES + 63) / 64;   // 782
    const int nblk32  = (N_NODES + 31) / 32;   // 1563

    // CSR build: reserve-based bucket partition (no global scan)
    hipMemsetAsync(bukcur, 0, 2 * NBUK * sizeof(int), stream);
    part_k<<<2 * NBLK, 256, 0, stream>>>(src_g, dst_g, rec_g,
                                         src_f, dst_f, rec_f, bukcur,
                                         features, mask, norm_g, y);
    p3_build_k<<<2 * NBUK, 512, 0, stream>>>(rec_g, rps_g, rpe_g, adj_g,
                                             rec_f, rps_f, rpe_f, adj_f, bukcur);

    // hb0 = fp16( ng * (relu( aggG(y)@W1 * ng + b1 ) @ wh) )   -- one kernel
    fused_mlp_k<<<gblocks, 256, 0, stream>>>(y, rps_g, rpe_g, adj_g,
                                             W1, b1, wh, norm_g, hb0, N_NODES);

    // sb0 = ((features*mask)@ws)*nf   (fp16 out)
    gemm_k<64, 64, 1, 2, 1><<<gblocks, 256, 0, stream>>>(features, mask, wsw, norm_f,
                                                         nullptr, (void*)sb0, N_NODES);

    // out = sigmoid(aggG(hb0)*ng + bh + aggF(sb0)*nf + bs)
    final2_k<<<nblk32, 256, 0, stream>>>(hb0, sb0, rps_g, rpe_g, adj_g,
                                         rps_f, rpe_f, adj_f,
                                         norm_g, norm_f, bh, bs, out);
}